// Round 16
// baseline (503.142 us; speedup 1.0000x reference)
//
#include <hip/hip_runtime.h>

#define H  64
#define TT 512
#define BB 512
#define CSTR 80    // hbuf chain stride in halves: 160B -> max 2-way bank aliasing
#define UCH 16     // chunk length (steps) for fused xp GEMM (= one M-tile)
#define XSTRF 260  // xp row stride in floats: 4*260 % 32 == 16 -> 2-way writes (free)

typedef _Float16 half8 __attribute__((ext_vector_type(8)));
typedef float    f32x4 __attribute__((ext_vector_type(4)));

__device__ __forceinline__ float frcp(float x) { return __builtin_amdgcn_rcpf(x); }
__device__ __forceinline__ float swz8(float v) {   // lane <- lane^8 (pairs within 16-lane groups)
    int r = __builtin_amdgcn_ds_swizzle(__builtin_bit_cast(int, v), 0x201F); // xor=8,and=0x1F
    return __builtin_bit_cast(float, r);
}

// ---------------------------------------------------------------------------
// xpad: [B*T][32] fp16, cols 0..3 = x (fp32->fp16), cols 4..31 = 0.
// ---------------------------------------------------------------------------
__global__ __launch_bounds__(256) void xpad_prep(const float* __restrict__ x,
                                                 _Float16* __restrict__ xpad) {
    int gid = blockIdx.x * 256 + threadIdx.x;
    int row = gid >> 2, q = gid & 3;
    half8 v = {0,0,0,0,0,0,0,0};
    if (q == 0) {
        float4 xv = ((const float4*)x)[row];
        v[0] = (_Float16)xv.x; v[1] = (_Float16)xv.y;
        v[2] = (_Float16)xv.z; v[3] = (_Float16)xv.w;
    }
    *(half8*)(xpad + (size_t)row * 32 + q * 8) = v;
}

// ---------------------------------------------------------------------------
// Shared cell-update: replica-pair activation dedup.
// All activations are f(x) = 1 - beta*rcp(exp(gamma*x)+1)  (sigm: b=g=1,
// tanh: b=g=2). Lane A (m<8): e_i=sigm(g0), e_g=tanh(g2). Lane B (m>=8):
// e_f=sigm(g1), e_o=sigm(g3). One ds_swizzle exchanges p_ig <-> e_f; c is
// updated identically on both lanes; B forms h and owns all stores.
// Trans ops: 10 -> 6 per lane-step.
// ---------------------------------------------------------------------------
__device__ __forceinline__ float cell_update(const f32x4& g_own, float& c,
                                             bool isA, float gb_g, float gb_b) {
    float ga = isA ? g_own[0] : g_own[1];
    float gb = isA ? g_own[2] : g_own[3];
    float ea = 1.f - frcp(__expf(ga) + 1.f);                 // sigm (both roles)
    float eb = 1.f - gb_b * frcp(__expf(gb * gb_g) + 1.f);   // A: tanh, B: sigm
    float pig_local = ea * eb;                                // A: e_i*e_g (B: junk)
    float send = isA ? pig_local : ea;                        // A sends p_ig, B sends e_f
    float recv = swz8(send);
    float ef  = isA ? recv : ea;
    float pig = isA ? pig_local : recv;
    c = __builtin_fmaf(ef, c, pig);
    float tc = 1.f - 2.f * frcp(__expf(2.f * c) + 1.f);      // tanh(c), both lanes
    return eb * tc;                                           // valid h on B lanes
}

// ---------------------------------------------------------------------------
// Layer 0 FUSED (R15 structure + activation dedup).
// ---------------------------------------------------------------------------
__global__ __launch_bounds__(256, 2) void lstm_l0(
    const _Float16* __restrict__ xpad,
    const float* __restrict__ WihF, const float* __restrict__ WhhF, const float* __restrict__ bF,
    const float* __restrict__ WihB, const float* __restrict__ WhhB, const float* __restrict__ bB,
    _Float16* __restrict__ out0)
{
    const int dir = blockIdx.x & 1;
    const int b0  = (blockIdx.x >> 1) * 2;
    const int tid = threadIdx.x;
    const int w = tid >> 6, l = tid & 63, m = l & 15, q = l >> 4;
    const int ch  = m & 1;
    const int ubo = (m >> 1) & 3;
    const int uo  = w * 16 + ubo * 4 + q;
    const bool isA = (m < 8);
    const bool act = (m >= 8);               // B lanes own stores now
    const float gb_g = isA ? 2.f : 1.f;      // act_b: tanh on A, sigm on B
    const float gb_b = isA ? 2.f : 1.f;

    const float* Wih = dir ? WihB : WihF;
    const float* Whh = dir ? WhhB : WhhF;
    const float* bia = dir ? bB   : bF;

    half8 Ah[4][2];
#pragma unroll
    for (int ub = 0; ub < 4; ++ub) {
        const int wrow = (m & 3) * 64 + (w * 16 + ub * 4 + (m >> 2));
#pragma unroll
        for (int s2 = 0; s2 < 2; ++s2) {
            const float* src = Whh + wrow * 64 + s2 * 32 + q * 8;
            half8 tmp;
#pragma unroll
            for (int j = 0; j < 8; ++j) tmp[j] = (_Float16)src[j];
            Ah[ub][s2] = tmp;
        }
    }

    half8 Bg[4];
    float bvj[4];
#pragma unroll
    for (int j = 0; j < 4; ++j) {
        const int n  = w * 64 + j * 16 + m;
        const int gr = (n & 3) * 64 + (n >> 2);
        bvj[j] = bia[gr];
        half8 tmp;
#pragma unroll
        for (int jj = 0; jj < 8; ++jj) {
            int k = q * 8 + jj;
            tmp[jj] = (k < 4) ? (_Float16)Wih[gr * 4 + k] : (_Float16)0.f;
        }
        Bg[j] = tmp;
    }

    __shared__ __align__(16) float xp[2][UCH][XSTRF];
    __shared__ _Float16 hbuf[2][2][CSTR];
    for (int i = tid; i < 2 * 2 * CSTR / 2; i += 256) ((unsigned int*)hbuf)[i] = 0u;
    __syncthreads();

    float c = 0.f;
    int p = 0;

    for (int chunk = 0; chunk < TT / UCH; ++chunk) {
        const int c0 = chunk * UCH;

        // Phase A (no barrier: wave-private xp cols)
#pragma unroll
        for (int cc = 0; cc < 2; ++cc) {
            const int tA = dir ? (TT - 1 - (c0 + m)) : (c0 + m);
            half8 a0 = *(const half8*)(xpad + (size_t)((b0 + cc) * TT + tA) * 32 + q * 8);
#pragma unroll
            for (int j = 0; j < 4; ++j) {
                f32x4 acc = {bvj[j], bvj[j], bvj[j], bvj[j]};
                acc = __builtin_amdgcn_mfma_f32_16x16x32_f16(a0, Bg[j], acc, 0, 0, 0);
#pragma unroll
                for (int i = 0; i < 4; ++i)
                    xp[cc][q * 4 + i][w * 64 + j * 16 + m] = acc[i];
            }
        }

        // Phase B
        f32x4 xv = *(const f32x4*)&xp[ch][0][uo * 4];
        for (int u = 0; u < UCH; ++u) {
            int un = (u + 1 < UCH) ? (u + 1) : u;
            f32x4 xn = *(const f32x4*)&xp[ch][un][uo * 4];

            half8 ah0 = *(const half8*)&hbuf[p][ch][q * 8];
            half8 ah1 = *(const half8*)&hbuf[p][ch][32 + q * 8];

            f32x4 g_own;
#pragma unroll
            for (int ub = 0; ub < 4; ++ub) {
                f32x4 a = __builtin_amdgcn_mfma_f32_16x16x32_f16(Ah[ub][0], ah0, xv, 0, 0, 0);
                a       = __builtin_amdgcn_mfma_f32_16x16x32_f16(Ah[ub][1], ah1, a, 0, 0, 0);
                if (ub == ubo) g_own = a;
            }

            float hh = cell_update(g_own, c, isA, gb_g, gb_b);

            if (act) {
                const int tg = dir ? (TT - 1 - (c0 + u)) : (c0 + u);
                out0[((size_t)(b0 + ch) * TT + tg) * 128 + dir * 64 + uo] = (_Float16)hh;
                hbuf[p ^ 1][ch][uo] = (_Float16)hh;
            }
            __syncthreads();
            p ^= 1; xv = xn;
        }
    }
}

// ---------------------------------------------------------------------------
// Layer 1 FUSED (R15 structure + activation dedup).
// ---------------------------------------------------------------------------
__global__ __launch_bounds__(256, 2) void lstm_l1(
    const _Float16* __restrict__ out0,
    const float* __restrict__ WihF, const float* __restrict__ WhhF, const float* __restrict__ bF,
    const float* __restrict__ WihB, const float* __restrict__ WhhB, const float* __restrict__ bB,
    float* __restrict__ pooled)
{
    const int dir = blockIdx.x & 1;
    const int b0  = (blockIdx.x >> 1) * 2;
    const int tid = threadIdx.x;
    const int w = tid >> 6, l = tid & 63, m = l & 15, q = l >> 4;
    const int ch  = m & 1;
    const int ubo = (m >> 1) & 3;
    const int uo  = w * 16 + ubo * 4 + q;
    const bool isA = (m < 8);
    const bool act = (m >= 8);
    const float gb_g = isA ? 2.f : 1.f;
    const float gb_b = isA ? 2.f : 1.f;

    const float* Wih = dir ? WihB : WihF;
    const float* Whh = dir ? WhhB : WhhF;
    const float* bia = dir ? bB   : bF;

    half8 Ah[4][2];
#pragma unroll
    for (int ub = 0; ub < 4; ++ub) {
        const int wrow = (m & 3) * 64 + (w * 16 + ub * 4 + (m >> 2));
#pragma unroll
        for (int s2 = 0; s2 < 2; ++s2) {
            const float* src = Whh + wrow * 64 + s2 * 32 + q * 8;
            half8 tmp;
#pragma unroll
            for (int j = 0; j < 8; ++j) tmp[j] = (_Float16)src[j];
            Ah[ub][s2] = tmp;
        }
    }

    half8 Bg[4][4];
    float bvj[4];
#pragma unroll
    for (int j = 0; j < 4; ++j) {
        const int n  = w * 64 + j * 16 + m;
        const int gr = (n & 3) * 64 + (n >> 2);
        bvj[j] = bia[gr];
#pragma unroll
        for (int k4 = 0; k4 < 4; ++k4) {
            const float* src = Wih + gr * 128 + k4 * 32 + q * 8;
            half8 tmp;
#pragma unroll
            for (int jj = 0; jj < 8; ++jj) tmp[jj] = (_Float16)src[jj];
            Bg[j][k4] = tmp;
        }
    }

    __shared__ __align__(16) float xp[2][UCH][XSTRF];
    __shared__ _Float16 hbuf[2][2][CSTR];
    for (int i = tid; i < 2 * 2 * CSTR / 2; i += 256) ((unsigned int*)hbuf)[i] = 0u;
    __syncthreads();

    float c = 0.f, hs = 0.f;
    int p = 0;

    for (int chunk = 0; chunk < TT / UCH; ++chunk) {
        const int c0 = chunk * UCH;

        // Phase A (no barrier: wave-private xp cols)
#pragma unroll
        for (int cc = 0; cc < 2; ++cc) {
            const int tA = dir ? (TT - 1 - (c0 + m)) : (c0 + m);
            const _Float16* arow = out0 + (size_t)((b0 + cc) * TT + tA) * 128 + q * 8;
            half8 a0 = *(const half8*)(arow);
            half8 a1 = *(const half8*)(arow + 32);
            half8 a2 = *(const half8*)(arow + 64);
            half8 a3 = *(const half8*)(arow + 96);
#pragma unroll
            for (int j = 0; j < 4; ++j) {
                f32x4 acc = {bvj[j], bvj[j], bvj[j], bvj[j]};
                acc = __builtin_amdgcn_mfma_f32_16x16x32_f16(a0, Bg[j][0], acc, 0, 0, 0);
                acc = __builtin_amdgcn_mfma_f32_16x16x32_f16(a1, Bg[j][1], acc, 0, 0, 0);
                acc = __builtin_amdgcn_mfma_f32_16x16x32_f16(a2, Bg[j][2], acc, 0, 0, 0);
                acc = __builtin_amdgcn_mfma_f32_16x16x32_f16(a3, Bg[j][3], acc, 0, 0, 0);
#pragma unroll
                for (int i = 0; i < 4; ++i)
                    xp[cc][q * 4 + i][w * 64 + j * 16 + m] = acc[i];
            }
        }

        // Phase B
        f32x4 xv = *(const f32x4*)&xp[ch][0][uo * 4];
        for (int u = 0; u < UCH; ++u) {
            int un = (u + 1 < UCH) ? (u + 1) : u;
            f32x4 xn = *(const f32x4*)&xp[ch][un][uo * 4];

            half8 ah0 = *(const half8*)&hbuf[p][ch][q * 8];
            half8 ah1 = *(const half8*)&hbuf[p][ch][32 + q * 8];

            f32x4 g_own;
#pragma unroll
            for (int ub = 0; ub < 4; ++ub) {
                f32x4 a = __builtin_amdgcn_mfma_f32_16x16x32_f16(Ah[ub][0], ah0, xv, 0, 0, 0);
                a       = __builtin_amdgcn_mfma_f32_16x16x32_f16(Ah[ub][1], ah1, a, 0, 0, 0);
                if (ub == ubo) g_own = a;
            }

            float hh = cell_update(g_own, c, isA, gb_g, gb_b);
            hs += hh;                                     // valid on B lanes

            if (act) hbuf[p ^ 1][ch][uo] = (_Float16)hh;
            __syncthreads();
            p ^= 1; xv = xn;
        }
    }

    if (act) pooled[(size_t)(b0 + ch) * 128 + dir * 64 + uo] = hs;
}

// ---------------------------------------------------------------------------
// Head: out[b] = dot(pooled[b], fcw) / T + fcb
// ---------------------------------------------------------------------------
__global__ __launch_bounds__(64) void fc_head(
    const float* __restrict__ pooled,
    const float* __restrict__ fcw, const float* __restrict__ fcb,
    float* __restrict__ out)
{
    const int b = blockIdx.x;
    const int l = threadIdx.x;
    float v = pooled[b * 128 + l] * fcw[l] + pooled[b * 128 + 64 + l] * fcw[64 + l];
#pragma unroll
    for (int o = 32; o > 0; o >>= 1) v += __shfl_down(v, o);
    if (l == 0) out[b] = v * (1.f / (float)TT) + fcb[0];
}

extern "C" void kernel_launch(void* const* d_in, const int* in_sizes, int n_in,
                              void* d_out, int out_size, void* d_ws, size_t ws_size,
                              hipStream_t stream) {
    const float* x       = (const float*)d_in[0];
    const float* Wih_l0f = (const float*)d_in[1];
    const float* Whh_l0f = (const float*)d_in[2];
    const float* b_l0f   = (const float*)d_in[3];
    const float* Wih_l0b = (const float*)d_in[4];
    const float* Whh_l0b = (const float*)d_in[5];
    const float* b_l0b   = (const float*)d_in[6];
    const float* Wih_l1f = (const float*)d_in[7];
    const float* Whh_l1f = (const float*)d_in[8];
    const float* b_l1f   = (const float*)d_in[9];
    const float* Wih_l1b = (const float*)d_in[10];
    const float* Whh_l1b = (const float*)d_in[11];
    const float* b_l1b   = (const float*)d_in[12];
    const float* fcw     = (const float*)d_in[13];
    const float* fcb     = (const float*)d_in[14];

    const size_t o_xpad   = 0;
    const size_t o_out0   = o_xpad + (size_t)BB * TT * 32 * 2;
    const size_t o_pooled = o_out0 + (size_t)BB * TT * 128 * 2;

    _Float16* xpad   = (_Float16*)((char*)d_ws + o_xpad);
    _Float16* out0   = (_Float16*)((char*)d_ws + o_out0);
    float*    pooled = (float*)((char*)d_ws + o_pooled);

    xpad_prep<<<(BB * TT * 4) / 256, 256, 0, stream>>>(x, xpad);
    lstm_l0<<<(BB / 2) * 2, 256, 0, stream>>>(xpad, Wih_l0f, Whh_l0f, b_l0f,
                                              Wih_l0b, Whh_l0b, b_l0b, out0);
    lstm_l1<<<(BB / 2) * 2, 256, 0, stream>>>(out0, Wih_l1f, Whh_l1f, b_l1f,
                                              Wih_l1b, Whh_l1b, b_l1b, pooled);
    fc_head<<<BB, 64, 0, stream>>>(pooled, fcw, fcb, (float*)d_out);
}